// Round 13
// baseline (275.477 us; speedup 1.0000x reference)
//
#include <hip/hip_runtime.h>
#include <hip/hip_bf16.h>
#include <math.h>

typedef __attribute__((ext_vector_type(4))) float f32x4;
typedef __attribute__((ext_vector_type(8))) short s16x8;
typedef __attribute__((ext_vector_type(4))) short s16x4;
typedef __hip_bfloat16 bf16;

#define MB (1024ull*1024ull)
// workspace layout (bytes) — total 53 MB
#define GATE_OFF    (0ull)
#define ACTW_OFF    (16ull*1024)
#define U_OFF       (20ull*1024)
#define CMEAN_OFF   (28ull*1024)    // 1024 f32 — atomic accumulator (zeroed in prepass)
#define PART_OFF    (64ull*1024)    // 8*2048 f32 ratt col partials
#define HIDDEN_OFF  (1ull*MB)
#define RATT_OFF    (5ull*MB)
#define CAND_OFF    (9ull*MB)
#define PREDS_OFF   (11ull*MB)
#define READ_OFF    (13ull*MB)
#define XBF_OFF     (17ull*MB)
#define WT_OFF      (19ull*MB)      // bf16 8192x1024 (16MB); READ2 aliases head after G1
#define CATT_OFF    (35ull*MB)      // bf16 3584x2048 (14MB)
#define MEMT_OFF    (49ull*MB)      // bf16 1024x2048 (4MB)
#define READ2_OFF   WT_OFF

__device__ __forceinline__ short f2bf_s(float f) {
    bf16 h = __float2bfloat16(f);
    return *reinterpret_cast<short*>(&h);
}

__device__ __forceinline__ void async_load16(const bf16* g, short* l) {
    __builtin_amdgcn_global_load_lds((const __attribute__((address_space(1))) void*)g,
                                     (__attribute__((address_space(3))) void*)l, 16, 0, 0);
}

__device__ __forceinline__ float fast_tanh(float x) {
    float e2x = __expf(2.f * x);
    return 1.f - 2.f / (e2x + 1.f);
}

// fast 9-way activation mix — __expf algebra only (validated round 9)
__device__ __forceinline__ float qact(float x, const float* w) {
    float ex  = __expf(x);
    float r1  = 1.f / (1.f + ex);
    float sig = 1.f - r1;
    float em1 = ex - 1.f;
    float elu = x > 0.f ? x : em1;
    float e2x = ex * ex;
    float th  = 1.f - 2.f / (e2x + 1.f);
    float rel = fmaxf(x, 0.f);
    float silu = x * sig;
    float u   = 0.7978845608028654f * (x + 0.044715f * x * x * x);
    float e2u = __expf(2.f * u);
    float gel = x * (1.f - 1.f / (e2u + 1.f));
    float sel = 1.0507009873554805f * (x > 0.f ? x : 1.6732632423543772f * em1);
    float t   = 1.f + ex;
    float t2  = t * t;
    float mish = x * (1.f - 2.f / (t2 + 1.f));
    return w[0]*sig + w[1]*elu + w[2]*th + w[3]*rel + w[4]*silu
         + w[5]*gel + w[6]*sel + w[7]*mish + w[8]*x;
}

// ---------------- fused prepass: cvt + gate + 5 transposes + cmacc zero ----------------
__device__ __forceinline__ void do_transpose(const float* __restrict__ in,
                                             bf16* __restrict__ out, int R, int C,
                                             int bx, int by, int t) {
    __shared__ short tile[64][66];
    int k0 = by*64, n0 = bx*64;
    int tx = t & 63, ty = t >> 6;
    #pragma unroll
    for (int j = 0; j < 16; j++) {
        int k = ty + j*4;
        tile[tx][k] = f2bf_s(in[(size_t)(k0 + k)*C + n0 + tx]);
    }
    __syncthreads();
    int kp = t & 31, nrow = t >> 5;
    #pragma unroll
    for (int jj = 0; jj < 8; jj++) {
        int n = nrow + jj*8;
        unsigned lo = (unsigned short)tile[n][kp*2];
        unsigned hi = (unsigned short)tile[n][kp*2 + 1];
        *reinterpret_cast<unsigned*>(&out[(size_t)(n0 + n)*R + k0 + kp*2]) = lo | (hi << 16);
    }
}

__global__ __launch_bounds__(256) void k_prepass(
        const float* __restrict__ x, bf16* __restrict__ xbf,
        const float* __restrict__ gw, const float* __restrict__ gb,
        const float* __restrict__ aw_in,
        float* __restrict__ gate, float* __restrict__ actw,
        float* __restrict__ cmacc,
        const float* __restrict__ w_, bf16* __restrict__ wT,
        const float* __restrict__ att_w, const float* __restrict__ write_w,
        const float* __restrict__ out_w, bf16* __restrict__ catT,
        const float* __restrict__ mem, bf16* __restrict__ memT) {
    int blk = blockIdx.x, t = threadIdx.x;
    if (blk < 1024) {
        int i = blk*256 + t;
        f32x4 v = ((const f32x4*)x)[i];
        s16x4 o;
        #pragma unroll
        for (int j = 0; j < 4; j++) o[j] = f2bf_s(v[j]);
        ((s16x4*)xbf)[i] = o;
        if (blk == 0 && t == 64) {
            float a[9]; float m = -1e30f;
            for (int i2 = 0; i2 < 9; i2++) { a[i2] = aw_in[i2]; m = fmaxf(m, a[i2]); }
            float ss = 0.f;
            for (int i2 = 0; i2 < 9; i2++) { a[i2] = __expf(a[i2]-m); ss += a[i2]; }
            float inv = 1.f / ss;
            for (int i2 = 0; i2 < 9; i2++) actw[i2] = a[i2]*inv;
        }
        if (blk == 2) ((f32x4*)cmacc)[t] = (f32x4){0.f, 0.f, 0.f, 0.f};   // zero 1024 floats
    } else if (blk < 2048) {
        int b = blk - 1024, w = t >> 6, lane = t & 63;
        __shared__ float l[4];
        float s = 0.f;
        for (int k = lane; k < 1024; k += 64)
            s += x[(size_t)b*1024 + k] * gw[k*4 + w];
        #pragma unroll
        for (int off = 32; off; off >>= 1) s += __shfl_xor(s, off);
        if (lane == 0) l[w] = s + gb[w];
        __syncthreads();
        if (t == 0) {
            float m = fmaxf(fmaxf(l[0], l[1]), fmaxf(l[2], l[3]));
            float e0 = __expf(l[0]-m), e1 = __expf(l[1]-m), e2 = __expf(l[2]-m), e3 = __expf(l[3]-m);
            float inv = 1.f / (e0+e1+e2+e3);
            gate[b*4+0] = e0*inv; gate[b*4+1] = e1*inv;
            gate[b*4+2] = e2*inv; gate[b*4+3] = e3*inv;
        }
    } else if (blk < 4096) {
        int rel = blk - 2048;
        do_transpose(w_, wT, 1024, 8192, rel & 127, rel >> 7, t);
    } else if (blk < 5120) {
        int rel = blk - 4096;
        do_transpose(att_w, catT, 2048, 2048, rel & 31, rel >> 5, t);
    } else if (blk < 5632) {
        int rel = blk - 5120;
        do_transpose(write_w, catT + 2048ull*2048, 2048, 1024, rel & 15, rel >> 4, t);
    } else if (blk < 5888) {
        int rel = blk - 5632;
        do_transpose(out_w, catT + 3072ull*2048, 2048, 512, rel & 7, rel >> 3, t);
    } else {
        int rel = blk - 5888;
        do_transpose(mem, memT, 2048, 1024, rel & 15, rel >> 4, t);
    }
}

// ---------------- GEMM (BT): C = A(MxK) @ Bt(NxK)^T, TMx128 tile, BK=32 ----------------
// Single-barrier double-buffered K-loop (validated round 12).
// MODE 5 additionally accumulates cand column sums into outF2 (cmacc) via LDS+atomics.
template <int MODE, int TM>
__global__ __launch_bounds__(256, 2) void gemm_bt(
        const bf16* __restrict__ A, const bf16* __restrict__ Bt,
        int K, int lda, int ldb, int kOffset,
        const float* __restrict__ bias, const float* __restrict__ bias2,
        const float* __restrict__ bias3,
        float* __restrict__ outF, float* __restrict__ outF2,
        bf16* __restrict__ outH, bf16* __restrict__ outH2,
        const float* __restrict__ gate, const float* __restrict__ actw,
        const float* __restrict__ mask, int outStride) {
    constexpr int MI = TM / 32;
    __shared__ __align__(16) union SMem {
        struct { short a[2][TM*32]; short b[2][128*32]; } tl;
        float z[TM*32];
    } sm;
    int t = threadIdx.x, lane = t & 63;
    int rowBase = blockIdx.y * TM, colBase = blockIdx.x * 128;
    int lm = lane & 15, lq = lane >> 4;
    int w = t >> 6;
    int qm = (w >> 1) * (TM/2), qn = (w & 1) * 64;

    A  += (size_t)kOffset * blockIdx.z;
    Bt += (size_t)kOffset * blockIdx.z;

    f32x4 acc[MI][4];
    #pragma unroll
    for (int i = 0; i < MI; i++)
        #pragma unroll
        for (int j = 0; j < 4; j++) acc[i][j] = (f32x4){0.f, 0.f, 0.f, 0.f};

    int cb0 = w*128 + lane, cb1 = cb0 + 64;
    int rb0 = cb0 >> 2, kb0 = (cb0 & 3) * 8;
    int rb1 = cb1 >> 2, kb1 = (cb1 & 3) * 8;
    int ca0 = (TM == 128) ? (w*128 + lane) : (w*64 + lane);
    int ra0 = ca0 >> 2, ka0 = (ca0 & 3) * 8;
    int ra1 = (ca0 + 64) >> 2, ka1 = ((ca0 + 64) & 3) * 8;   // TM=128 only

    auto issueLoads = [&](int k0, int ib) {
        short* bA = sm.tl.a[ib];
        short* bB = sm.tl.b[ib];
        async_load16(A + (size_t)(rowBase + ra0)*lda + k0 + ka0,
                     bA + ((TM == 128) ? w*1024 : w*512));
        if (TM == 128)
            async_load16(A + (size_t)(rowBase + ra1)*lda + k0 + ka1, bA + w*1024 + 512);
        async_load16(Bt + (size_t)(colBase + rb0)*ldb + k0 + kb0, bB + w*1024);
        async_load16(Bt + (size_t)(colBase + rb1)*ldb + k0 + kb1, bB + w*1024 + 512);
    };

    issueLoads(0, 0);
    int ib = 0;
    for (int k0 = 0; k0 < K; k0 += 32) {
        __syncthreads();                    // drains vmcnt: buf[ib] ready; buf[ib^1] free
        if (k0 + 32 < K) issueLoads(k0 + 32, ib ^ 1);
        const short* cA = sm.tl.a[ib];
        const short* cB = sm.tl.b[ib];
        s16x8 af[MI], bfr[4];
        #pragma unroll
        for (int mi = 0; mi < MI; mi++)
            af[mi] = *reinterpret_cast<const s16x8*>(cA + (qm + mi*16 + lm)*32 + lq*8);
        #pragma unroll
        for (int ni = 0; ni < 4; ni++)
            bfr[ni] = *reinterpret_cast<const s16x8*>(cB + (qn + ni*16 + lm)*32 + lq*8);
        #pragma unroll
        for (int mi = 0; mi < MI; mi++)
            #pragma unroll
            for (int ni = 0; ni < 4; ni++)
                acc[mi][ni] = __builtin_amdgcn_mfma_f32_16x16x32_bf16(af[mi], bfr[ni], acc[mi][ni], 0, 0, 0);
        ib ^= 1;
    }

    if (MODE == 4) {
        __syncthreads();   // all tile reads done; safe to overlay sm.z
        #pragma unroll
        for (int mi = 0; mi < MI; mi++) {
            int rowl0 = qm + mi*16 + lq*4;
            #pragma unroll
            for (int ni = 0; ni < 4; ni++) {
                int col = colBase + qn + ni*16 + lm;
                int n = col & 3;
                float bb = bias[col];
                f32x4 v = acc[mi][ni];
                #pragma unroll
                for (int r = 0; r < 4; r++) v[r] = (v[r] + bb) * gate[(rowBase + rowl0 + r)*4 + n];
                #pragma unroll
                for (int r = 0; r < 4; r++) v[r] += __shfl_xor(v[r], 1);
                #pragma unroll
                for (int r = 0; r < 4; r++) v[r] += __shfl_xor(v[r], 2);
                if ((lane & 3) == 0) {
                    int ul = ((w & 1) << 4) + ni*4 + (lm >> 2);
                    #pragma unroll
                    for (int r = 0; r < 4; r++)
                        sm.z[(rowl0 + r)*32 + ul] = v[r];
                }
            }
        }
        __syncthreads();
        float aw[9];
        #pragma unroll
        for (int i = 0; i < 9; i++) aw[i] = actw[i];
        int u0 = colBase >> 2;
        #pragma unroll
        for (int i = 0; i < TM/8; i++) {
            int idx = t + i*256;
            int row = idx >> 5, ul = idx & 31;
            int ug = u0 + ul;
            float zz = sm.z[idx];
            outH[(size_t)(rowBase + row)*outStride + ug] = __float2bfloat16(qact(zz, aw) * mask[ug]);
        }
    } else if (MODE == 5) {
        float csum[4] = {0.f, 0.f, 0.f, 0.f};
        bool isCand = (colBase >= 2048) && (colBase < 3072);
        #pragma unroll
        for (int mi = 0; mi < MI; mi++) {
            int row0 = rowBase + qm + mi*16 + lq*4;
            #pragma unroll
            for (int ni = 0; ni < 4; ni++) {
                int col = colBase + qn + ni*16 + lm;
                if (col < 2048) {
                    float bb = bias[col];
                    #pragma unroll
                    for (int r = 0; r < 4; r++)
                        outH[(size_t)(row0 + r)*2048 + col] = __float2bfloat16(acc[mi][ni][r] + bb);
                } else if (col < 3072) {
                    int c = col - 2048;
                    float bb = bias2[c];
                    #pragma unroll
                    for (int r = 0; r < 4; r++) {
                        float tv = fast_tanh(acc[mi][ni][r] + bb);
                        csum[ni] += tv;
                        outH2[(size_t)(row0 + r)*1024 + c] = __float2bfloat16(tv);
                    }
                } else {
                    int c = col - 3072;
                    float bb = bias3[c];
                    #pragma unroll
                    for (int r = 0; r < 4; r++)
                        outF[(size_t)(row0 + r)*512 + c] = acc[mi][ni][r] + bb;
                }
            }
        }
        if (isCand) {
            // per-block column sums -> one global atomic per column
            __syncthreads();                 // tiles dead; reuse sm.z[0..127]
            if (t < 128) sm.z[t] = 0.f;
            __syncthreads();
            #pragma unroll
            for (int ni = 0; ni < 4; ni++)
                atomicAdd(&sm.z[qn + ni*16 + lm], csum[ni]);
            __syncthreads();
            if (t < 128)
                atomicAdd(&outF2[(colBase - 2048) + t], sm.z[t]);
        }
    } else {  // MODE 3 (split-K partial)
        float* of = blockIdx.z ? outF2 : outF;
        #pragma unroll
        for (int mi = 0; mi < MI; mi++) {
            int row0 = rowBase + qm + mi*16 + lq*4;
            #pragma unroll
            for (int ni = 0; ni < 4; ni++) {
                int col = colBase + qn + ni*16 + lm;
                #pragma unroll
                for (int r = 0; r < 4; r++)
                    of[(size_t)(row0 + r)*outStride + col] = acc[mi][ni][r];
            }
        }
    }
}

// ---------------- in-place row softmax over 2048 cols (bf16 buffer) ----------------
__global__ __launch_bounds__(256) void k_softmax(bf16* __restrict__ ratt) {
    int b = blockIdx.x, t = threadIdx.x, w = t >> 6, lane = t & 63;
    __shared__ float red[8];
    bf16* row = ratt + (size_t)b*2048;
    float v[8];
    float mx = -1e30f;
    #pragma unroll
    for (int j = 0; j < 8; j++) {
        v[j] = __bfloat162float(row[t + j*256]);
        mx = fmaxf(mx, v[j]);
    }
    #pragma unroll
    for (int off = 32; off; off >>= 1) mx = fmaxf(mx, __shfl_xor(mx, off));
    if (lane == 0) red[w] = mx;
    __syncthreads();
    mx = fmaxf(fmaxf(red[0], red[1]), fmaxf(red[2], red[3]));
    float s = 0.f;
    #pragma unroll
    for (int j = 0; j < 8; j++) { v[j] = __expf(v[j] - mx); s += v[j]; }
    #pragma unroll
    for (int off = 32; off; off >>= 1) s += __shfl_xor(s, off);
    if (lane == 0) red[4 + w] = s;
    __syncthreads();
    float inv = 1.f / (red[4] + red[5] + red[6] + red[7]);
    #pragma unroll
    for (int j = 0; j < 8; j++)
        row[t + j*256] = __float2bfloat16(v[j] * inv);
}

// ---------------- ratt column partials (8x8 grid) ----------------
__global__ __launch_bounds__(256) void k_colpart(const bf16* __restrict__ ratt,
                                                 float* __restrict__ part) {
    int ct = blockIdx.x, rc = blockIdx.y, t = threadIdx.x;
    int col = ct*256 + t;                     // 0..2047
    float s = 0.f;
    int r0 = rc*128;
    for (int r = 0; r < 128; r++)
        s += __bfloat162float(ratt[(size_t)(r0 + r)*2048 + col]);
    part[rc*2048 + col] = s;
}

__global__ __launch_bounds__(256) void k_colfin(const float* __restrict__ part,
                                                const float* __restrict__ update_gate,
                                                float* __restrict__ u) {
    int col = blockIdx.x*256 + threadIdx.x;   // 0..2047
    float s = 0.f;
    #pragma unroll
    for (int rc = 0; rc < 8; rc++) s += part[rc*2048 + col];
    u[col] = (s * (1.f/1024.f)) * update_gate[col];
}

// ---------------- new_mem blend (f32 out); cmacc scaled inline ----------------
__global__ __launch_bounds__(256) void k_newmem(const float* __restrict__ mem,
                                                const float* __restrict__ u,
                                                const float* __restrict__ cmacc,
                                                float* __restrict__ out1) {
    int idx = blockIdx.x*256 + threadIdx.x;
    int m = idx >> 10, d = idx & 1023;
    float um = u[m];
    out1[idx] = mem[idx] * (1.f - um) + um * (cmacc[d] * (1.f/1024.f));
}

// ---------------- critic: 2 rows/block, f32x4 weight loads (round-10 validated) ----------------
__global__ __launch_bounds__(256) void k_critic(
        const float* __restrict__ readv, const float* __restrict__ readv2,
        const float* __restrict__ preds, const bf16* __restrict__ hidden,
        const float* cw1, const float* cb1, const float* cw2, const float* cb2,
        const float* cw3, const float* cb3, const float* cw4, const float* cb4,
        const float* cw5, const float* cb5, const float* thr,
        float* __restrict__ out0) {
    __shared__ __align__(16) float sx[2*1024];
    __shared__ __align__(16) float sp[2*512];
    __shared__ __align__(16) short sh[2*2048];
    __shared__ __align__(16) f32x4 part[2][32][8];
    __shared__ float feat[2][96];
    __shared__ float fused[2][64];
    __shared__ float gsh[2];
    int b0 = blockIdx.x * 2, t = threadIdx.x;
    int j4 = t & 7, kg = t >> 3;

    ((f32x4*)sx)[t]       = ((const f32x4*)(readv + (size_t)b0*1024))[t]
                          + ((const f32x4*)(readv2 + (size_t)b0*1024))[t];
    ((f32x4*)sx)[t + 256] = ((const f32x4*)(readv + (size_t)b0*1024))[t + 256]
                          + ((const f32x4*)(readv2 + (size_t)b0*1024))[t + 256];
    ((f32x4*)sp)[t]       = ((const f32x4*)(preds + (size_t)b0*512))[t];
    ((s16x8*)sh)[t]       = ((const s16x8*)(hidden + (size_t)b0*2048))[t];
    ((s16x8*)sh)[t + 256] = ((const s16x8*)(hidden + (size_t)b0*2048))[t + 256];
    __syncthreads();

    {
        const f32x4* wv = (const f32x4*)cw1;
        f32x4 a0 = (f32x4){0,0,0,0}, a1 = (f32x4){0,0,0,0};
        int k0 = kg*32;
        #pragma unroll 4
        for (int k = k0; k < k0 + 32; k++) {
            f32x4 wq = wv[k*8 + j4];
            a0 += sx[k] * wq;
            a1 += sx[1024 + k] * wq;
        }
        part[0][kg][j4] = a0; part[1][kg][j4] = a1;
    }
    __syncthreads();
    if (t < 64) {
        int r = t >> 5, f = t & 31;
        float s = 0.f;
        #pragma unroll
        for (int i = 0; i < 32; i++) s += part[r][i][f >> 2][f & 3];
        feat[r][f] = fmaxf(s + cb1[f], 0.f);
    }
    __syncthreads();
    {
        const f32x4* wv = (const f32x4*)cw2;
        f32x4 a0 = (f32x4){0,0,0,0}, a1 = (f32x4){0,0,0,0};
        int k0 = kg*16;
        #pragma unroll 4
        for (int k = k0; k < k0 + 16; k++) {
            f32x4 wq = wv[k*8 + j4];
            a0 += sp[k] * wq;
            a1 += sp[512 + k] * wq;
        }
        part[0][kg][j4] = a0; part[1][kg][j4] = a1;
    }
    __syncthreads();
    if (t < 64) {
        int r = t >> 5, f = t & 31;
        float s = 0.f;
        #pragma unroll
        for (int i = 0; i < 32; i++) s += part[r][i][f >> 2][f & 3];
        feat[r][32 + f] = fmaxf(s + cb2[f], 0.f);
    }
    __syncthreads();
    {
        const f32x4* wv = (const f32x4*)cw3;
        f32x4 a0 = (f32x4){0,0,0,0}, a1 = (f32x4){0,0,0,0};
        int k0 = kg*64;
        #pragma unroll 4
        for (int k = k0; k < k0 + 64; k++) {
            f32x4 wq = wv[k*8 + j4];
            float h0 = __bfloat162float(*reinterpret_cast<const bf16*>(&sh[k]));
            float h1 = __bfloat162float(*reinterpret_cast<const bf16*>(&sh[2048 + k]));
            a0 += h0 * wq;
            a1 += h1 * wq;
        }
        part[0][kg][j4] = a0; part[1][kg][j4] = a1;
    }
    __syncthreads();
    if (t < 64) {
        int r = t >> 5, f = t & 31;
        float s = 0.f;
        #pragma unroll
        for (int i = 0; i < 32; i++) s += part[r][i][f >> 2][f & 3];
        feat[r][64 + f] = fmaxf(s + cb3[f], 0.f);
    }
    __syncthreads();
    if (t < 128) {
        int r = t >> 6, uu = t & 63;
        float s = 0.f;
        #pragma unroll 8
        for (int k = 0; k < 96; k++) s += feat[r][k] * cw4[k*64 + uu];
        fused[r][uu] = fmaxf(s + cb4[uu], 0.f);
    }
    __syncthreads();
    if (t < 128) {
        int r = t >> 6, lane = t & 63;
        float v = fused[r][lane] * cw5[lane*2];
        #pragma unroll
        for (int off = 32; off; off >>= 1) v += __shfl_xor(v, off);
        if (lane == 0)
            gsh[r] = 1.f / (1.f + __expf(-(v + cb5[0] - thr[0])));
    }
    __syncthreads();
    #pragma unroll
    for (int idx = t; idx < 1024; idx += 256) {
        int r = idx >> 9, o = idx & 511;
        out0[(size_t)(b0 + r)*512 + o] = sp[r*512 + o] * gsh[r];
    }
}

extern "C" void kernel_launch(void* const* d_in, const int* in_sizes, int n_in,
                              void* d_out, int out_size, void* d_ws, size_t ws_size,
                              hipStream_t stream) {
    const float* x        = (const float*)d_in[0];
    const float* w_       = (const float*)d_in[1];
    const float* b_bias   = (const float*)d_in[2];
    const float* gate_w   = (const float*)d_in[3];
    const float* gate_b   = (const float*)d_in[4];
    const float* act_w    = (const float*)d_in[5];
    const float* mask     = (const float*)d_in[6];
    const float* mem      = (const float*)d_in[7];
    const float* att_w    = (const float*)d_in[8];
    const float* att_b    = (const float*)d_in[9];
    const float* write_w  = (const float*)d_in[10];
    const float* write_b  = (const float*)d_in[11];
    const float* upd_gate = (const float*)d_in[12];
    const float* out_w    = (const float*)d_in[13];
    const float* out_b    = (const float*)d_in[14];
    const float* cw1 = (const float*)d_in[15]; const float* cb1 = (const float*)d_in[16];
    const float* cw2 = (const float*)d_in[17]; const float* cb2 = (const float*)d_in[18];
    const float* cw3 = (const float*)d_in[19]; const float* cb3 = (const float*)d_in[20];
    const float* cw4 = (const float*)d_in[21]; const float* cb4 = (const float*)d_in[22];
    const float* cw5 = (const float*)d_in[23]; const float* cb5 = (const float*)d_in[24];
    const float* thr = (const float*)d_in[25];

    char* ws = (char*)d_ws;
    float* gate   = (float*)(ws + GATE_OFF);
    float* actw   = (float*)(ws + ACTW_OFF);
    float* uvec   = (float*)(ws + U_OFF);
    float* cmacc  = (float*)(ws + CMEAN_OFF);
    float* part   = (float*)(ws + PART_OFF);
    bf16*  hidden = (bf16*)(ws + HIDDEN_OFF);
    bf16*  ratt   = (bf16*)(ws + RATT_OFF);
    bf16*  cand   = (bf16*)(ws + CAND_OFF);
    float* preds  = (float*)(ws + PREDS_OFF);
    float* readv  = (float*)(ws + READ_OFF);
    float* readv2 = (float*)(ws + READ2_OFF);   // aliases wT head (dead after G1)
    bf16*  xbf    = (bf16*)(ws + XBF_OFF);
    bf16*  wT     = (bf16*)(ws + WT_OFF);
    bf16*  catT   = (bf16*)(ws + CATT_OFF);
    bf16*  memT   = (bf16*)(ws + MEMT_OFF);

    float* out0 = (float*)d_out;            // (1024, 512)
    float* out1 = out0 + 1024*512;          // (2048, 1024)

    // fused prepass: cvt + gate + all 5 transposes + cmacc zero (one dispatch)
    k_prepass<<<6400, 256, 0, stream>>>(x, xbf, gate_w, gate_b, act_w, gate, actw, cmacc,
        w_, wT, att_w, write_w, out_w, catT, mem, memT);

    // G1: hidden = qact((x@w + b)·gate) * mask     [M=1024, N=8192, K=1024] — TM=128, 512 blocks
    gemm_bt<4, 128><<<dim3(64, 8), 256, 0, stream>>>(xbf, wT, 1024, 1024, 1024, 0,
        b_bias, nullptr, nullptr, nullptr, nullptr, hidden, nullptr, gate, actw, mask, 2048);
    // G234 fused: [att|write|out] heads + cand colsum  [M=1024, N=3584, K=2048] — 448 blocks
    gemm_bt<5, 64><<<dim3(28, 16), 256, 0, stream>>>(hidden, catT, 2048, 2048, 2048, 0,
        att_b, write_b, out_b, preds, cmacc, ratt, cand, nullptr, nullptr, nullptr, 0);
    k_softmax<<<1024, 256, 0, stream>>>(ratt);
    // G5: read = ratt @ mem, split-K=2             [M=1024, N=1024, K=2x1024] — 256 blocks
    gemm_bt<3, 64><<<dim3(8, 16, 2), 256, 0, stream>>>(ratt, memT, 1024, 2048, 2048, 1024,
        nullptr, nullptr, nullptr, readv, readv2, nullptr, nullptr, nullptr, nullptr, nullptr, 1024);

    k_colpart<<<dim3(8, 8), 256, 0, stream>>>(ratt, part);
    k_colfin<<<8, 256, 0, stream>>>(part, upd_gate, uvec);
    k_newmem<<<8192, 256, 0, stream>>>(mem, uvec, cmacc, out1);
    k_critic<<<512, 256, 0, stream>>>(readv, readv2, preds, hidden,
        cw1, cb1, cw2, cb2, cw3, cb3, cw4, cb4, cw5, cb5, thr, out0);
}